// Round 1
// baseline (146.015 us; speedup 1.0000x reference)
//
#include <hip/hip_runtime.h>
#include <hip/hip_bf16.h>

#define LPOS 8192
#define HDIM 128
#define M_TOT 4096        // B*Cin
#define N_EXT 144         // 128 + 16 (col 128 = ones -> sum(x); 129..143 zero)
#define KSPLIT 16
#define KCHUNK (LPOS / KSPLIT)
#define K1_LS 16

typedef float  f32x4 __attribute__((ext_vector_type(4)));
typedef short  s16x8 __attribute__((ext_vector_type(8)));
typedef unsigned int u32x4 __attribute__((ext_vector_type(4)));

__device__ __forceinline__ unsigned short bf16_rne(float f) {
    unsigned u = __builtin_bit_cast(unsigned, f);
    u += 0x7fffu + ((u >> 16) & 1u);
    return (unsigned short)(u >> 16);
}

// ---------------- Kernel 1: SIREN -> h2T (bf16) [N_EXT][LPOS] ----------------
// rows 0..127 : h2[l][h] = sin(30*(dot(h1[l], w2[h]) + b2[h])),
//               h1[l][j] = sin(30*(rel_l*w1[j] + b1[j]))
// row 128     : 1.0  (so g[:,128] = sum_l x -> carries the b3 term)
// rows 129+   : 0.0
__global__ __launch_bounds__(128) void k1_siren(
        const float* __restrict__ w1, const float* __restrict__ b1,
        const float* __restrict__ w2, const float* __restrict__ b2,
        unsigned short* __restrict__ h2T) {
    __shared__ float w2s[HDIM * 129];                 // +1 pad: bank-conflict-free
    __shared__ __align__(16) float h1s[HDIM * K1_LS]; // [j][ls]
    __shared__ unsigned short h2s[HDIM * (K1_LS + 2)];
    const int tid = threadIdx.x;

    for (int idx = tid; idx < HDIM * HDIM; idx += 128)
        w2s[(idx >> 7) * 129 + (idx & 127)] = w2[idx];

    const float myw1 = w1[tid];
    const float myb1 = b1[tid];
    const float myb2 = b2[tid];
    const int l0 = blockIdx.x * K1_LS;

    #pragma unroll
    for (int ls = 0; ls < K1_LS; ls++) {
        float rel = -1.0f + (2.0f / 8191.0f) * (float)(l0 + ls);
        h1s[tid * K1_LS + ls] = sinf(30.0f * (rel * myw1 + myb1));
    }
    __syncthreads();

    float acc[K1_LS];
    #pragma unroll
    for (int ls = 0; ls < K1_LS; ls++) acc[ls] = myb2;

    for (int j = 0; j < HDIM; j++) {
        float wv = w2s[tid * 129 + j];
        const f32x4* hp = (const f32x4*)&h1s[j * K1_LS];
        f32x4 h0 = hp[0], h1 = hp[1], h2 = hp[2], h3 = hp[3];
        acc[0]  += wv * h0[0]; acc[1]  += wv * h0[1]; acc[2]  += wv * h0[2]; acc[3]  += wv * h0[3];
        acc[4]  += wv * h1[0]; acc[5]  += wv * h1[1]; acc[6]  += wv * h1[2]; acc[7]  += wv * h1[3];
        acc[8]  += wv * h2[0]; acc[9]  += wv * h2[1]; acc[10] += wv * h2[2]; acc[11] += wv * h2[3];
        acc[12] += wv * h3[0]; acc[13] += wv * h3[1]; acc[14] += wv * h3[2]; acc[15] += wv * h3[3];
    }

    #pragma unroll
    for (int ls = 0; ls < K1_LS; ls++)
        h2s[tid * (K1_LS + 2) + ls] = bf16_rne(sinf(30.0f * acc[ls]));
    __syncthreads();

    u32x4 o0, o1;
    const int base = tid * (K1_LS + 2);
    #pragma unroll
    for (int q = 0; q < 4; q++) {
        o0[q] = (unsigned)h2s[base + 2 * q]     | ((unsigned)h2s[base + 2 * q + 1] << 16);
        o1[q] = (unsigned)h2s[base + 8 + 2 * q] | ((unsigned)h2s[base + 9 + 2 * q] << 16);
    }
    *(u32x4*)(h2T + (size_t)tid * LPOS + l0)     = o0;
    *(u32x4*)(h2T + (size_t)tid * LPOS + l0 + 8) = o1;

    if (tid < 16) {  // extension rows
        unsigned v = (tid == 0) ? 0x3F803F80u : 0u;
        u32x4 ov = { v, v, v, v };
        *(u32x4*)(h2T + (size_t)(HDIM + tid) * LPOS + l0)     = ov;
        *(u32x4*)(h2T + (size_t)(HDIM + tid) * LPOS + l0 + 8) = ov;
    }
}

// ---------------- Kernel 2: g[m][h] = sum_l x[m][l]*h2e[l][h]  (MFMA bf16) ----
// M=4096, N=144, K=8192 split into KSPLIT chunks; atomicAdd partials into g.
__global__ __launch_bounds__(256) void k2_gemm(
        const float* __restrict__ x, const unsigned short* __restrict__ h2T,
        float* __restrict__ g) {
    const int lane = threadIdx.x & 63;
    const int wv   = threadIdx.x >> 6;
    const int r    = lane & 15;
    const int kg   = lane >> 4;
    const int m0   = blockIdx.x * 64 + wv * 16;
    const int kc   = blockIdx.y * KCHUNK;

    const float* xp = x + (size_t)(m0 + r) * LPOS + kc + kg * 8;
    const unsigned short* hp = h2T + kc + kg * 8;

    f32x4 acc[9];
    #pragma unroll
    for (int t = 0; t < 9; t++) { f32x4 z = {0.f, 0.f, 0.f, 0.f}; acc[t] = z; }

    for (int kk = 0; kk < KCHUNK; kk += 32) {
        f32x4 a0 = *(const f32x4*)(xp + kk);
        f32x4 a1 = *(const f32x4*)(xp + kk + 4);
        s16x8 af;
        af[0] = (short)bf16_rne(a0[0]); af[1] = (short)bf16_rne(a0[1]);
        af[2] = (short)bf16_rne(a0[2]); af[3] = (short)bf16_rne(a0[3]);
        af[4] = (short)bf16_rne(a1[0]); af[5] = (short)bf16_rne(a1[1]);
        af[6] = (short)bf16_rne(a1[2]); af[7] = (short)bf16_rne(a1[3]);
        #pragma unroll
        for (int t = 0; t < 9; t++) {
            const s16x8 bf = *(const s16x8*)(hp + (size_t)(t * 16 + r) * LPOS + kk);
            acc[t] = __builtin_amdgcn_mfma_f32_16x16x32_bf16(af, bf, acc[t], 0, 0, 0);
        }
    }

    // C/D layout (verified): col = lane&15, row = (lane>>4)*4 + q
    #pragma unroll
    for (int t = 0; t < 9; t++) {
        const int col = t * 16 + r;
        #pragma unroll
        for (int q = 0; q < 4; q++) {
            const int row = m0 + kg * 4 + q;
            unsafeAtomicAdd(&g[(size_t)row * N_EXT + col], acc[t][q]);
        }
    }
}

// ---------------- Kernel 3: out[b,o] = sum_{i,h<=128} g[b,i,h]*w3e[o*64+i,h] --
__global__ __launch_bounds__(256) void k3_contract(
        const float* __restrict__ g, const float* __restrict__ w3,
        const float* __restrict__ b3, const float* __restrict__ bias,
        float* __restrict__ out) {
    const int b = blockIdx.x >> 6;
    const int o = blockIdx.x & 63;
    __shared__ float red[256];
    float acc = 0.0f;
    for (int idx = threadIdx.x; idx < 64 * 129; idx += 256) {
        int i = idx / 129;
        int h = idx - i * 129;
        float gv = g[(size_t)(b * 64 + i) * N_EXT + h];
        float wvv = (h < HDIM) ? w3[(size_t)(o * 64 + i) * HDIM + h] : b3[o * 64 + i];
        acc += gv * wvv;
    }
    red[threadIdx.x] = acc;
    __syncthreads();
    for (int s = 128; s > 0; s >>= 1) {
        if (threadIdx.x < s) red[threadIdx.x] += red[threadIdx.x + s];
        __syncthreads();
    }
    if (threadIdx.x == 0) out[blockIdx.x] = red[0] + bias[o];
}

extern "C" void kernel_launch(void* const* d_in, const int* in_sizes, int n_in,
                              void* d_out, int out_size, void* d_ws, size_t ws_size,
                              hipStream_t stream) {
    const float* x    = (const float*)d_in[0];
    const float* w1   = (const float*)d_in[1];
    const float* b1   = (const float*)d_in[2];
    const float* w2   = (const float*)d_in[3];
    const float* b2   = (const float*)d_in[4];
    const float* w3   = (const float*)d_in[5];
    const float* b3   = (const float*)d_in[6];
    const float* bias = (const float*)d_in[7];
    float* out = (float*)d_out;

    unsigned short* h2T = (unsigned short*)d_ws;
    const size_t H2T_BYTES = (size_t)N_EXT * LPOS * 2;   // 2.36 MB
    float* g = (float*)((char*)d_ws + H2T_BYTES);
    const size_t G_BYTES = (size_t)M_TOT * N_EXT * 4;    // 2.36 MB

    hipMemsetAsync(g, 0, G_BYTES, stream);
    k1_siren<<<LPOS / K1_LS, 128, 0, stream>>>(w1, b1, w2, b2, h2T);
    k2_gemm<<<dim3(M_TOT / 64, KSPLIT), 256, 0, stream>>>(x, h2T, g);
    k3_contract<<<64 * 64, 256, 0, stream>>>(g, w3, b3, bias, out);
}

// Round 2
// 100.920 us; speedup vs baseline: 1.4468x; 1.4468x over previous
//
#include <hip/hip_runtime.h>
#include <hip/hip_bf16.h>

#define LPOS 8192
#define HDIM 128
#define M_TOT 4096        // B*Cin
#define N_EXT 144         // 128 + 16 (col 128 = ones -> sum(x); 129..143 zero)
#define KSPLIT 16
#define KCHUNK (LPOS / KSPLIT)   // 512
#define K1_LS 16
#define UNITS_PER_CHUNK (8 * N_EXT)   // 1152 16-byte units per 64-k chunk

typedef float  f32x4 __attribute__((ext_vector_type(4)));
typedef short  s16x8 __attribute__((ext_vector_type(8)));
typedef unsigned int u32x4 __attribute__((ext_vector_type(4)));

__device__ __forceinline__ unsigned short bf16_rne(float f) {
    unsigned u = __builtin_bit_cast(unsigned, f);
    u += 0x7fffu + ((u >> 16) & 1u);
    return (unsigned short)(u >> 16);
}

// ---------------- Kernel 1: SIREN -> h2T in LDS-image layout ----------------
// h2T as 16-B units: unit index = chunk*1152 + k8*144 + row
//   chunk = l/64, k8 = (l/8)%8, row = h (0..127), rows 128..143 = {1.0 row, zeros}
__global__ __launch_bounds__(128) void k1_siren(
        const float* __restrict__ w1, const float* __restrict__ b1,
        const float* __restrict__ w2, const float* __restrict__ b2,
        unsigned short* __restrict__ h2T) {
    __shared__ float w2s[HDIM * 129];                 // +1 pad: bank-conflict-free
    __shared__ __align__(16) float h1s[HDIM * K1_LS]; // [j][ls]
    __shared__ unsigned short h2s[HDIM * (K1_LS + 2)];
    const int tid = threadIdx.x;

    for (int idx = tid; idx < HDIM * HDIM; idx += 128)
        w2s[(idx >> 7) * 129 + (idx & 127)] = w2[idx];

    const float myw1 = w1[tid];
    const float myb1 = b1[tid];
    const float myb2 = b2[tid];
    const int l0 = blockIdx.x * K1_LS;

    #pragma unroll
    for (int ls = 0; ls < K1_LS; ls++) {
        float rel = -1.0f + (2.0f / 8191.0f) * (float)(l0 + ls);
        h1s[tid * K1_LS + ls] = sinf(30.0f * (rel * myw1 + myb1));
    }
    __syncthreads();

    float acc[K1_LS];
    #pragma unroll
    for (int ls = 0; ls < K1_LS; ls++) acc[ls] = myb2;

    for (int j = 0; j < HDIM; j++) {
        float wv = w2s[tid * 129 + j];
        const f32x4* hp = (const f32x4*)&h1s[j * K1_LS];
        f32x4 h0 = hp[0], h1 = hp[1], h2 = hp[2], h3 = hp[3];
        acc[0]  += wv * h0[0]; acc[1]  += wv * h0[1]; acc[2]  += wv * h0[2]; acc[3]  += wv * h0[3];
        acc[4]  += wv * h1[0]; acc[5]  += wv * h1[1]; acc[6]  += wv * h1[2]; acc[7]  += wv * h1[3];
        acc[8]  += wv * h2[0]; acc[9]  += wv * h2[1]; acc[10] += wv * h2[2]; acc[11] += wv * h2[3];
        acc[12] += wv * h3[0]; acc[13] += wv * h3[1]; acc[14] += wv * h3[2]; acc[15] += wv * h3[3];
    }

    #pragma unroll
    for (int ls = 0; ls < K1_LS; ls++)
        h2s[tid * (K1_LS + 2) + ls] = bf16_rne(sinf(30.0f * acc[ls]));
    __syncthreads();

    u32x4 o0, o1;
    const int base = tid * (K1_LS + 2);
    #pragma unroll
    for (int q = 0; q < 4; q++) {
        o0[q] = (unsigned)h2s[base + 2 * q]     | ((unsigned)h2s[base + 2 * q + 1] << 16);
        o1[q] = (unsigned)h2s[base + 8 + 2 * q] | ((unsigned)h2s[base + 9 + 2 * q] << 16);
    }
    const size_t c  = (size_t)(l0 >> 6);
    const int    k8 = (l0 >> 3) & 7;   // even; this block covers k8 and k8+1
    *(u32x4*)(h2T + (c * UNITS_PER_CHUNK + (size_t)k8       * N_EXT + tid) * 8) = o0;
    *(u32x4*)(h2T + (c * UNITS_PER_CHUNK + (size_t)(k8 + 1) * N_EXT + tid) * 8) = o1;

    if (tid < 16) {  // extension rows 128..143
        unsigned v = (tid == 0) ? 0x3F803F80u : 0u;
        u32x4 ov = { v, v, v, v };
        *(u32x4*)(h2T + (c * UNITS_PER_CHUNK + (size_t)k8       * N_EXT + 128 + tid) * 8) = ov;
        *(u32x4*)(h2T + (c * UNITS_PER_CHUNK + (size_t)(k8 + 1) * N_EXT + 128 + tid) * 8) = ov;
    }
}

// ---------------- Kernel 2: g[m][h] = sum_l x[m][l]*h2e[l][h]  (MFMA bf16) ----
// M=4096 (64 blocks x 64-row tile), N=144, K split 16-way; B staged in LDS
// double-buffered via global_load_lds; atomicAdd partials into g.
__global__ __launch_bounds__(256) void k2_gemm(
        const float* __restrict__ x, const unsigned short* __restrict__ h2T,
        float* __restrict__ g) {
    __shared__ unsigned short lds[2][UNITS_PER_CHUNK * 8];  // 2 x 18432 B

    const int lane = threadIdx.x & 63;
    const int wv   = threadIdx.x >> 6;
    const int r    = lane & 15;
    const int kg   = lane >> 4;
    const int m0   = blockIdx.x * 64 + wv * 16;
    const int kc   = blockIdx.y * KCHUNK;
    const int c0   = kc >> 6;          // first 64-k chunk index
    const int NIT  = KCHUNK / 64;      // 8

    const float* xp = x + (size_t)(m0 + r) * LPOS + kc + kg * 8;
    const unsigned short* stage_src = h2T + ((size_t)lane) * 8;

    // stage chunk (c0+ci) into buffer b: contiguous 18432-B copy, linear LDS
    auto stage = [&](int ci, int b) {
        const unsigned short* src = stage_src + (size_t)(c0 + ci) * UNITS_PER_CHUNK * 8;
        #pragma unroll
        for (int u0 = wv * 64; u0 < UNITS_PER_CHUNK; u0 += 256) {
            __builtin_amdgcn_global_load_lds(
                (const unsigned int*)(src + (size_t)u0 * 8),
                (unsigned int*)&lds[b][u0 * 8], 16, 0, 0);
        }
    };

    f32x4 acc[9];
    #pragma unroll
    for (int t = 0; t < 9; t++) { f32x4 z = {0.f, 0.f, 0.f, 0.f}; acc[t] = z; }

    stage(0, 0);
    __syncthreads();

    for (int it = 0; it < NIT; ++it) {
        const float* xk = xp + it * 64;
        f32x4 a0 = *(const f32x4*)(xk);
        f32x4 a1 = *(const f32x4*)(xk + 4);
        f32x4 a2 = *(const f32x4*)(xk + 32);
        f32x4 a3 = *(const f32x4*)(xk + 36);

        if (it + 1 < NIT) stage(it + 1, (it + 1) & 1);

        s16x8 aflo, afhi;
        aflo[0] = (short)bf16_rne(a0[0]); aflo[1] = (short)bf16_rne(a0[1]);
        aflo[2] = (short)bf16_rne(a0[2]); aflo[3] = (short)bf16_rne(a0[3]);
        aflo[4] = (short)bf16_rne(a1[0]); aflo[5] = (short)bf16_rne(a1[1]);
        aflo[6] = (short)bf16_rne(a1[2]); aflo[7] = (short)bf16_rne(a1[3]);
        afhi[0] = (short)bf16_rne(a2[0]); afhi[1] = (short)bf16_rne(a2[1]);
        afhi[2] = (short)bf16_rne(a2[2]); afhi[3] = (short)bf16_rne(a2[3]);
        afhi[4] = (short)bf16_rne(a3[0]); afhi[5] = (short)bf16_rne(a3[1]);
        afhi[6] = (short)bf16_rne(a3[2]); afhi[7] = (short)bf16_rne(a3[3]);

        const unsigned short* buf = &lds[it & 1][0];
        #pragma unroll
        for (int t = 0; t < 9; t++) {
            s16x8 blo = *(const s16x8*)(buf + ((kg    ) * N_EXT + t * 16 + r) * 8);
            s16x8 bhi = *(const s16x8*)(buf + ((kg + 4) * N_EXT + t * 16 + r) * 8);
            acc[t] = __builtin_amdgcn_mfma_f32_16x16x32_bf16(aflo, blo, acc[t], 0, 0, 0);
            acc[t] = __builtin_amdgcn_mfma_f32_16x16x32_bf16(afhi, bhi, acc[t], 0, 0, 0);
        }
        __syncthreads();   // drains stage vmcnt + barrier; next buffer ready
    }

    // C/D layout: col = lane&15, row = (lane>>4)*4 + q
    #pragma unroll
    for (int t = 0; t < 9; t++) {
        const int col = t * 16 + r;
        #pragma unroll
        for (int q = 0; q < 4; q++) {
            const int row = m0 + kg * 4 + q;
            unsafeAtomicAdd(&g[(size_t)row * N_EXT + col], acc[t][q]);
        }
    }
}

// ---------------- Kernel 3: out[b,o] = sum_{i,h<=128} g[b,i,h]*w3e[o*64+i,h] --
__global__ __launch_bounds__(256) void k3_contract(
        const float* __restrict__ g, const float* __restrict__ w3,
        const float* __restrict__ b3, const float* __restrict__ bias,
        float* __restrict__ out) {
    const int b = blockIdx.x >> 6;
    const int o = blockIdx.x & 63;
    __shared__ float red[256];
    float acc = 0.0f;
    for (int idx = threadIdx.x; idx < 64 * 129; idx += 256) {
        int i = idx / 129;
        int h = idx - i * 129;
        float gv = g[(size_t)(b * 64 + i) * N_EXT + h];
        float wvv = (h < HDIM) ? w3[(size_t)(o * 64 + i) * HDIM + h] : b3[o * 64 + i];
        acc += gv * wvv;
    }
    red[threadIdx.x] = acc;
    __syncthreads();
    for (int s = 128; s > 0; s >>= 1) {
        if (threadIdx.x < s) red[threadIdx.x] += red[threadIdx.x + s];
        __syncthreads();
    }
    if (threadIdx.x == 0) out[blockIdx.x] = red[0] + bias[o];
}

extern "C" void kernel_launch(void* const* d_in, const int* in_sizes, int n_in,
                              void* d_out, int out_size, void* d_ws, size_t ws_size,
                              hipStream_t stream) {
    const float* x    = (const float*)d_in[0];
    const float* w1   = (const float*)d_in[1];
    const float* b1   = (const float*)d_in[2];
    const float* w2   = (const float*)d_in[3];
    const float* b2   = (const float*)d_in[4];
    const float* w3   = (const float*)d_in[5];
    const float* b3   = (const float*)d_in[6];
    const float* bias = (const float*)d_in[7];
    float* out = (float*)d_out;

    unsigned short* h2T = (unsigned short*)d_ws;
    const size_t H2T_BYTES = (size_t)(LPOS / 64) * UNITS_PER_CHUNK * 16;  // 2.36 MB
    float* g = (float*)((char*)d_ws + H2T_BYTES);
    const size_t G_BYTES = (size_t)M_TOT * N_EXT * 4;                     // 2.36 MB

    hipMemsetAsync(g, 0, G_BYTES, stream);
    k1_siren<<<LPOS / K1_LS, 128, 0, stream>>>(w1, b1, w2, b2, h2T);
    k2_gemm<<<dim3(M_TOT / 64, KSPLIT), 256, 0, stream>>>(x, h2T, g);
    k3_contract<<<64 * 64, 256, 0, stream>>>(g, w3, b3, bias, out);
}